// Round 9
// baseline (611.158 us; speedup 1.0000x reference)
//
#include <hip/hip_runtime.h>
#include <hip/hip_bf16.h>
#include <math.h>

#define BB 32
#define LL 4096
#define HH 512
#define TM 32    // rows per block tile

typedef __attribute__((ext_vector_type(8))) short short8;
typedef __attribute__((ext_vector_type(8))) unsigned short u16x8;
typedef __attribute__((ext_vector_type(4))) float f32x4;

__device__ __forceinline__ unsigned short f2bf(float f) {
  __hip_bfloat16 h = __float2bfloat16(f);
  unsigned short u;
  __builtin_memcpy(&u, &h, 2);
  return u;
}
__device__ __forceinline__ float bf2f(unsigned short u) {
  unsigned int x = ((unsigned int)u) << 16;
  float f;
  __builtin_memcpy(&f, &x, 4);
  return f;
}
__device__ __forceinline__ float fast_tanh(float x) {
  float e = __expf(2.f * x);
  return 1.f - 2.f / (e + 1.f);
}

// ---------------------------------------------------------------------------
// prep: fused {base + ctx-zero | wvf fragment pack}. grid 192, block 256
// ---------------------------------------------------------------------------
__global__ __launch_bounds__(256) void prep_kernel(
    const float* __restrict__ query, const float* __restrict__ Wq,
    const float* __restrict__ bias, const float* __restrict__ conv_b,
    const float* __restrict__ Wv, float* __restrict__ base,
    unsigned short* __restrict__ wvf, float* __restrict__ ctx) {
  const int bid = blockIdx.x;
  if (bid < 64) {
    const int b = bid >> 1;
    const int o = ((bid & 1) << 8) + threadIdx.x;
    __shared__ float qrow[HH];
    for (int i = threadIdx.x; i < HH; i += 256) qrow[i] = query[b * HH + i];
    __syncthreads();
    const float* wq = Wq + (size_t)o * HH;
    float acc = 0.f;
    for (int h = 0; h < HH; h += 4) {
      float4 w = *(const float4*)(wq + h);
      acc += w.x * qrow[h] + w.y * qrow[h + 1] + w.z * qrow[h + 2] + w.w * qrow[h + 3];
    }
    base[b * HH + o] = acc + bias[o] + conv_b[o];
    ctx[b * HH + o] = 0.f;
  } else {
    const int chunk = (bid - 64) * 256 + threadIdx.x;
    const int l = chunk & 63;
    const int kk = (chunk >> 6) & 15;
    const int nb = chunk >> 10;
    const int row = nb * 16 + (l & 15);
    const int colf = kk * 32 + (l >> 4) * 8;
    const float* src = Wv + (size_t)row * HH + colf;
    u16x8 v;
    #pragma unroll
    for (int j = 0; j < 8; ++j) v[j] = f2bf(src[j]);
    *(u16x8*)(wvf + (size_t)chunk * 8) = v;
  }
}

// ---------------------------------------------------------------------------
// main: EXACT round-4 best-known kernel (225 us). grid (128,32), block 512
// ---------------------------------------------------------------------------
__global__ __launch_bounds__(512, 6) void main_kernel(
    const float* __restrict__ value, const float* __restrict__ last_attn,
    const float* __restrict__ conv_w, const unsigned short* __restrict__ wvf,
    const float* __restrict__ Ws, const float* __restrict__ bs,
    const float* __restrict__ base, float* __restrict__ ctx,
    float* __restrict__ attn) {
  const int b = blockIdx.y;
  const int l0 = blockIdx.x * TM;
  const int tid = threadIdx.x;
  const int w = tid >> 6;
  const int lane = tid & 63;
  const int g = lane >> 4;
  const int r16 = lane & 15;

  __shared__ __align__(16) unsigned short A[TM * HH];
  __shared__ float la_s[TM + 2];
  __shared__ float scorered[8][TM];
  __shared__ float srow[TM];
  __shared__ float ctxsum[HH];

  char* Ab = (char*)A;

  const float* vsrc = value + (size_t)(b * LL + l0) * HH;
  #pragma unroll
  for (int i = 0; i < 4; ++i) {
    const int c = tid + i * 512;
    const int row = c >> 6;
    const int cb = c & 63;
    const float4* s4 = (const float4*)(vsrc + (size_t)row * HH + cb * 8);
    float4 lo = s4[0], hi = s4[1];
    u16x8 v;
    v[0] = f2bf(lo.x); v[1] = f2bf(lo.y); v[2] = f2bf(lo.z); v[3] = f2bf(lo.w);
    v[4] = f2bf(hi.x); v[5] = f2bf(hi.y); v[6] = f2bf(hi.z); v[7] = f2bf(hi.w);
    const int off = row * 1024 + ((cb * 16) ^ ((row & 7) << 4));
    *(u16x8*)(Ab + off) = v;
  }
  ctxsum[tid] = 0.f;
  if (tid < TM + 2) {
    int l = l0 - 1 + tid;
    la_s[tid] = (l >= 0 && l < LL) ? last_attn[b * LL + l] : 0.f;
  }
  __syncthreads();

  f32x4 acc[2][4] = {};
  #pragma unroll 2
  for (int kk = 0; kk < 16; ++kk) {
    const int co = kk * 64 + g * 16;
    const int row0 = r16, row1 = 16 + r16;
    short8 a0 = *(const short8*)(Ab + row0 * 1024 + (co ^ ((row0 & 7) << 4)));
    short8 a1 = *(const short8*)(Ab + row1 * 1024 + (co ^ ((row1 & 7) << 4)));
    #pragma unroll
    for (int n = 0; n < 4; ++n) {
      short8 bf = *(const short8*)(wvf + ((size_t)((w * 4 + n) * 16 + kk) * 64 + lane) * 8);
      acc[0][n] = __builtin_amdgcn_mfma_f32_16x16x32_bf16(a0, bf, acc[0][n], 0, 0, 0);
      acc[1][n] = __builtin_amdgcn_mfma_f32_16x16x32_bf16(a1, bf, acc[1][n], 0, 0, 0);
    }
  }

  float basev[4], wsv[4], cw0v[4], cw1v[4], cw2v[4];
  #pragma unroll
  for (int n = 0; n < 4; ++n) {
    const int col = w * 64 + n * 16 + r16;
    basev[n] = base[b * HH + col];
    wsv[n]  = Ws[col];
    cw0v[n] = conv_w[col * 3 + 0];
    cw1v[n] = conv_w[col * 3 + 1];
    cw2v[n] = conv_w[col * 3 + 2];
  }
  #pragma unroll
  for (int m = 0; m < 2; ++m) {
    #pragma unroll
    for (int j = 0; j < 4; ++j) {
      const int row = m * 16 + g * 4 + j;
      const float lam = la_s[row], laz = la_s[row + 1], lap = la_s[row + 2];
      float sum = 0.f;
      #pragma unroll
      for (int n = 0; n < 4; ++n) {
        float e = acc[m][n][j] + basev[n] + cw0v[n] * lam + cw1v[n] * laz + cw2v[n] * lap;
        sum += fast_tanh(e) * wsv[n];
      }
      sum += __shfl_xor(sum, 1, 64);
      sum += __shfl_xor(sum, 2, 64);
      sum += __shfl_xor(sum, 4, 64);
      sum += __shfl_xor(sum, 8, 64);
      if (r16 == 0) scorered[w][row] = sum;
    }
  }
  __syncthreads();
  if (tid < TM) {
    float sc = bs[0];
    #pragma unroll
    for (int ww = 0; ww < 8; ++ww) sc += scorered[ww][tid];
    float s = 1.f / (1.f + __expf(-sc));
    srow[tid] = s;
    attn[b * LL + l0 + tid] = s;
  }
  __syncthreads();

  {
    float cacc[8];
    #pragma unroll
    for (int k = 0; k < 8; ++k) cacc[k] = 0.f;
    #pragma unroll
    for (int i = 0; i < 4; ++i) {
      const int row = w * 4 + i;
      const int off = row * 1024 + ((lane * 16) ^ ((row & 7) << 4));
      u16x8 v = *(const u16x8*)(Ab + off);
      const float s = srow[row];
      #pragma unroll
      for (int k = 0; k < 8; ++k) cacc[k] += s * bf2f(v[k]);
    }
    #pragma unroll
    for (int k = 0; k < 8; ++k) atomicAdd(&ctxsum[lane * 8 + k], cacc[k]);
  }
  __syncthreads();
  atomicAdd(&ctx[b * HH + tid], ctxsum[tid]);
}

// ---------------------------------------------------------------------------
// probe_kernel<V>: phase-ablated clones of main (write ONLY to scratch).
// V=1 stage only; V=2 stage+K-loop; V=3 stage+epilogue+ctx (acc opaqued 0);
// V=5 stage+K-loop with B-frags loaded once (B traffic /16).
// Same LDS footprint (shared arena) so occupancy matches main.
// ---------------------------------------------------------------------------
template <int V>
__global__ __launch_bounds__(512, 6) void probe_kernel(
    const float* __restrict__ value, const float* __restrict__ last_attn,
    const float* __restrict__ conv_w, const unsigned short* __restrict__ wvf,
    const float* __restrict__ Ws, const float* __restrict__ bs,
    const float* __restrict__ base, float* __restrict__ pctx,
    float* __restrict__ psink) {
  const int b = blockIdx.y;
  const int gx = blockIdx.x;
  const int l0 = gx * TM;
  const int tid = threadIdx.x;
  const int w = tid >> 6;
  const int lane = tid & 63;
  const int g = lane >> 4;
  const int r16 = lane & 15;

  __shared__ __align__(16) char smem[36352];   // same size as main's LDS
  char* Ab = smem;
  unsigned short* A = (unsigned short*)smem;
  float* la_s = (float*)(smem + 32768);              // 34 floats
  float (*scorered)[TM] = (float(*)[TM])(smem + 32912);
  float* srow = (float*)(smem + 33936);
  float* ctxsum = (float*)(smem + 34064);

  // ---- stage (all variants) ----
  const float* vsrc = value + (size_t)(b * LL + l0) * HH;
  #pragma unroll
  for (int i = 0; i < 4; ++i) {
    const int c = tid + i * 512;
    const int row = c >> 6;
    const int cb = c & 63;
    const float4* s4 = (const float4*)(vsrc + (size_t)row * HH + cb * 8);
    float4 lo = s4[0], hi = s4[1];
    u16x8 v;
    v[0] = f2bf(lo.x); v[1] = f2bf(lo.y); v[2] = f2bf(lo.z); v[3] = f2bf(lo.w);
    v[4] = f2bf(hi.x); v[5] = f2bf(hi.y); v[6] = f2bf(hi.z); v[7] = f2bf(hi.w);
    const int off = row * 1024 + ((cb * 16) ^ ((row & 7) << 4));
    *(u16x8*)(Ab + off) = v;
  }
  ctxsum[tid] = 0.f;
  if (tid < TM + 2) {
    int l = l0 - 1 + tid;
    la_s[tid] = (l >= 0 && l < LL) ? last_attn[b * LL + l] : 0.f;
  }
  __syncthreads();

  f32x4 acc[2][4] = {};

  if constexpr (V == 2 || V == 5) {
    if constexpr (V == 5) {
      short8 bfc[4];
      #pragma unroll
      for (int n = 0; n < 4; ++n)
        bfc[n] = *(const short8*)(wvf + ((size_t)((w * 4 + n) * 16 + 0) * 64 + lane) * 8);
      #pragma unroll 2
      for (int kk = 0; kk < 16; ++kk) {
        const int co = kk * 64 + g * 16;
        const int row0 = r16, row1 = 16 + r16;
        short8 a0 = *(const short8*)(Ab + row0 * 1024 + (co ^ ((row0 & 7) << 4)));
        short8 a1 = *(const short8*)(Ab + row1 * 1024 + (co ^ ((row1 & 7) << 4)));
        #pragma unroll
        for (int n = 0; n < 4; ++n) {
          acc[0][n] = __builtin_amdgcn_mfma_f32_16x16x32_bf16(a0, bfc[n], acc[0][n], 0, 0, 0);
          acc[1][n] = __builtin_amdgcn_mfma_f32_16x16x32_bf16(a1, bfc[n], acc[1][n], 0, 0, 0);
        }
      }
    } else {
      #pragma unroll 2
      for (int kk = 0; kk < 16; ++kk) {
        const int co = kk * 64 + g * 16;
        const int row0 = r16, row1 = 16 + r16;
        short8 a0 = *(const short8*)(Ab + row0 * 1024 + (co ^ ((row0 & 7) << 4)));
        short8 a1 = *(const short8*)(Ab + row1 * 1024 + (co ^ ((row1 & 7) << 4)));
        #pragma unroll
        for (int n = 0; n < 4; ++n) {
          short8 bf = *(const short8*)(wvf + ((size_t)((w * 4 + n) * 16 + kk) * 64 + lane) * 8);
          acc[0][n] = __builtin_amdgcn_mfma_f32_16x16x32_bf16(a0, bf, acc[0][n], 0, 0, 0);
          acc[1][n] = __builtin_amdgcn_mfma_f32_16x16x32_bf16(a1, bf, acc[1][n], 0, 0, 0);
        }
      }
    }
    // keep all acc live (rule 17), cheap sink
    float s = 0.f;
    #pragma unroll
    for (int m = 0; m < 2; ++m)
      #pragma unroll
      for (int n = 0; n < 4; ++n)
        s += acc[m][n][0] + acc[m][n][1] + acc[m][n][2] + acc[m][n][3];
    asm volatile("" :: "v"(s));
    if (tid == 0) psink[b * 128 + gx] = s;
  }

  if constexpr (V == 3) {
    // opaque the zero accumulators so epilogue isn't const-folded
    #pragma unroll
    for (int m = 0; m < 2; ++m)
      #pragma unroll
      for (int n = 0; n < 4; ++n)
        #pragma unroll
        for (int j = 0; j < 4; ++j) {
          float t = acc[m][n][j];
          asm volatile("" : "+v"(t));
          acc[m][n][j] = t;
        }
    float basev[4], wsv[4], cw0v[4], cw1v[4], cw2v[4];
    #pragma unroll
    for (int n = 0; n < 4; ++n) {
      const int col = w * 64 + n * 16 + r16;
      basev[n] = base[b * HH + col];
      wsv[n]  = Ws[col];
      cw0v[n] = conv_w[col * 3 + 0];
      cw1v[n] = conv_w[col * 3 + 1];
      cw2v[n] = conv_w[col * 3 + 2];
    }
    #pragma unroll
    for (int m = 0; m < 2; ++m) {
      #pragma unroll
      for (int j = 0; j < 4; ++j) {
        const int row = m * 16 + g * 4 + j;
        const float lam = la_s[row], laz = la_s[row + 1], lap = la_s[row + 2];
        float sum = 0.f;
        #pragma unroll
        for (int n = 0; n < 4; ++n) {
          float e = acc[m][n][j] + basev[n] + cw0v[n] * lam + cw1v[n] * laz + cw2v[n] * lap;
          sum += fast_tanh(e) * wsv[n];
        }
        sum += __shfl_xor(sum, 1, 64);
        sum += __shfl_xor(sum, 2, 64);
        sum += __shfl_xor(sum, 4, 64);
        sum += __shfl_xor(sum, 8, 64);
        if (r16 == 0) scorered[w][row] = sum;
      }
    }
    __syncthreads();
    if (tid < TM) {
      float sc = bs[0];
      #pragma unroll
      for (int ww = 0; ww < 8; ++ww) sc += scorered[ww][tid];
      srow[tid] = 1.f / (1.f + __expf(-sc));
    }
    __syncthreads();
    {
      float cacc[8];
      #pragma unroll
      for (int k = 0; k < 8; ++k) cacc[k] = 0.f;
      #pragma unroll
      for (int i = 0; i < 4; ++i) {
        const int row = w * 4 + i;
        const int off = row * 1024 + ((lane * 16) ^ ((row & 7) << 4));
        u16x8 v = *(const u16x8*)(Ab + off);
        const float s = srow[row];
        #pragma unroll
        for (int k = 0; k < 8; ++k) cacc[k] += s * bf2f(v[k]);
      }
      #pragma unroll
      for (int k = 0; k < 8; ++k) atomicAdd(&ctxsum[lane * 8 + k], cacc[k]);
    }
    __syncthreads();
    atomicAdd(&pctx[b * HH + tid], ctxsum[tid]);
  }

  if constexpr (V == 1) {
    // dynamic-ish readback so staging stores can't be DCE'd
    const int ro = (tid * 67) & 2047;
    u16x8 vv = *(const u16x8*)(Ab + ro * 16);
    float f = bf2f(vv[0]) + bf2f(vv[7]);
    asm volatile("" :: "v"(f));
    if (tid == 0) psink[b * 128 + gx] = f;
  }

  // keep all smem regions allocated in every variant (runtime-false guard)
  if (bs[0] > 1.0e30f)
    psink[0] = scorered[0][0] + srow[0] + la_s[0] + ctxsum[0] + bf2f(A[0]);
}

// ---------------------------------------------------------------------------
// finalize: per batch: S = sum_l s; attn /= S; out = [ctx/S, query]
// ---------------------------------------------------------------------------
__global__ __launch_bounds__(512) void finalize_kernel(
    const float* __restrict__ query, const float* __restrict__ ctx,
    float* __restrict__ out, float* __restrict__ attn) {
  const int b = blockIdx.x;
  const int tid = threadIdx.x;
  __shared__ float red[8];
  float s = 0.f;
  for (int l = tid; l < LL; l += 512) s += attn[b * LL + l];
  #pragma unroll
  for (int off = 32; off > 0; off >>= 1) s += __shfl_xor(s, off, 64);
  if ((tid & 63) == 0) red[tid >> 6] = s;
  __syncthreads();
  float S = 0.f;
  #pragma unroll
  for (int i = 0; i < 8; ++i) S += red[i];
  const float inv = 1.f / S;
  out[b * 2 * HH + tid] = ctx[b * HH + tid] * inv;
  out[b * 2 * HH + HH + tid] = query[b * HH + tid];
  for (int l = tid; l < LL; l += 512) attn[b * LL + l] *= inv;
}

// ---------------------------------------------------------------------------
extern "C" void kernel_launch(void* const* d_in, const int* in_sizes, int n_in,
                              void* d_out, int out_size, void* d_ws, size_t ws_size,
                              hipStream_t stream) {
  const float* query     = (const float*)d_in[0];
  const float* value     = (const float*)d_in[1];
  const float* last_attn = (const float*)d_in[2];
  const float* conv_w    = (const float*)d_in[3];
  const float* conv_b    = (const float*)d_in[4];
  const float* Wq        = (const float*)d_in[5];
  const float* Wv        = (const float*)d_in[6];
  const float* Ws        = (const float*)d_in[7];
  const float* bs        = (const float*)d_in[8];
  const float* bias      = (const float*)d_in[9];

  float* out  = (float*)d_out;                 // (B, 2H)
  float* attn = out + BB * 2 * HH;             // (B, L)
  float* base = (float*)d_ws;                               // B*H f32
  float* ctx  = base + BB * HH;                              // B*H f32
  unsigned short* wvf = (unsigned short*)(ctx + BB * HH);    // 512*512 bf16
  float* pctx  = (float*)(wvf + HH * HH);                    // B*H probe scratch
  float* psink = pctx + BB * HH;                             // 4096 floats

  // ---- real pipeline (exact round-4 best known) ----
  prep_kernel<<<192, 256, 0, stream>>>(query, Wq, bias, conv_b, Wv, base, wvf, ctx);
  dim3 grid(LL / TM, BB);
  main_kernel<<<grid, 512, 0, stream>>>(value, last_attn, conv_w, wvf, Ws, bs,
                                        base, ctx, attn);
  finalize_kernel<<<BB, 512, 0, stream>>>(query, ctx, out, attn);

  // ---- ablation probes (scratch-only; evidence for next round) ----
  hipMemsetAsync(pctx, 0, BB * HH * sizeof(float), stream);
  probe_kernel<1><<<grid, 512, 0, stream>>>(value, last_attn, conv_w, wvf, Ws, bs, base, pctx, psink);
  probe_kernel<2><<<grid, 512, 0, stream>>>(value, last_attn, conv_w, wvf, Ws, bs, base, pctx, psink);
  probe_kernel<3><<<grid, 512, 0, stream>>>(value, last_attn, conv_w, wvf, Ws, bs, base, pctx, psink);
  probe_kernel<5><<<grid, 512, 0, stream>>>(value, last_attn, conv_w, wvf, Ws, bs, base, pctx, psink);
}

// Round 10
// 243.651 us; speedup vs baseline: 2.5083x; 2.5083x over previous
//
#include <hip/hip_runtime.h>
#include <hip/hip_bf16.h>
#include <math.h>

#define BB 32
#define LL 4096
#define HH 512
#define TM 32    // rows per tile
#define NT 2     // consecutive tiles per block

typedef __attribute__((ext_vector_type(8))) short short8;
typedef __attribute__((ext_vector_type(8))) unsigned short u16x8;
typedef __attribute__((ext_vector_type(4))) float f32x4;

// manual RNE f32->bf16 (inputs finite randn; no NaN path needed)
__device__ __forceinline__ unsigned short f2bf(float f) {
  unsigned int x;
  __builtin_memcpy(&x, &f, 4);
  x += 0x7fffu + ((x >> 16) & 1u);
  return (unsigned short)(x >> 16);
}
__device__ __forceinline__ float bf2f(unsigned short u) {
  unsigned int x = ((unsigned int)u) << 16;
  float f;
  __builtin_memcpy(&f, &x, 4);
  return f;
}
__device__ __forceinline__ float fast_tanh(float x) {
  float e = __expf(2.f * x);
  return 1.f - 2.f / (e + 1.f);
}

// ---------------------------------------------------------------------------
// prep: fused {base | wvf fragment pack}. grid 192, block 256
// wvf wave-major layout: frag f = (w*16 + kk)*4 + n at wvf[(f*64+lane)*8]
// holds Wv[w*64 + n*16 + (lane&15)][kk*32 + (lane>>4)*8 + j], j=0..7.
// A wave's whole B working set is one contiguous 64 KB run; the 4 frags of
// one kk step are one contiguous 4 KB run.
// ---------------------------------------------------------------------------
__global__ __launch_bounds__(256) void prep_kernel(
    const float* __restrict__ query, const float* __restrict__ Wq,
    const float* __restrict__ bias, const float* __restrict__ conv_b,
    const float* __restrict__ Wv, float* __restrict__ base,
    unsigned short* __restrict__ wvf) {
  const int bid = blockIdx.x;
  if (bid < 64) {
    const int b = bid >> 1;
    const int o = ((bid & 1) << 8) + threadIdx.x;
    __shared__ float qrow[HH];
    for (int i = threadIdx.x; i < HH; i += 256) qrow[i] = query[b * HH + i];
    __syncthreads();
    const float* wq = Wq + (size_t)o * HH;
    float acc = 0.f;
    for (int h = 0; h < HH; h += 4) {
      float4 w = *(const float4*)(wq + h);
      acc += w.x * qrow[h] + w.y * qrow[h + 1] + w.z * qrow[h + 2] + w.w * qrow[h + 3];
    }
    base[b * HH + o] = acc + bias[o] + conv_b[o];
  } else {
    const int chunk = (bid - 64) * 256 + threadIdx.x;   // 0..32767
    const int lane = chunk & 63;
    const int f = chunk >> 6;          // 0..511 = w*64 + kk*4 + n
    const int n = f & 3;
    const int kk = (f >> 2) & 15;
    const int w = f >> 6;
    const int row = w * 64 + n * 16 + (lane & 15);
    const int colf = kk * 32 + (lane >> 4) * 8;
    const float* src = Wv + (size_t)row * HH + colf;
    u16x8 v;
    #pragma unroll
    for (int j = 0; j < 8; ++j) v[j] = f2bf(src[j]);
    *(u16x8*)(wvf + (size_t)chunk * 8) = v;
  }
}

// ---------------------------------------------------------------------------
// main: block = (b, 2 consecutive 32-row tiles at gx*64). 512 thr = 8 waves,
// wave w owns cols [w*64, w*64+64). Single 32 KiB swizzled A buffer;
// tile-1 global loads issued after tile-0's scorered barrier (acc/consts
// dead -> no spill), written after ctx-0 frees the buffer (T14 split).
// ctxsum LDS atomics padded (lane*9+k) -> 2-way banks. setprio on MFMA (T5).
// grid (64, 32), block 512
// ---------------------------------------------------------------------------
__global__ __launch_bounds__(512, 6) void main_kernel(
    const float* __restrict__ value, const float* __restrict__ last_attn,
    const float* __restrict__ conv_w, const unsigned short* __restrict__ wvf,
    const float* __restrict__ Ws, const float* __restrict__ bs,
    const float* __restrict__ base, float* __restrict__ ctxp,
    float* __restrict__ attn) {
  const int b = blockIdx.y;
  const int gx = blockIdx.x;
  const int tid = threadIdx.x;
  const int w = tid >> 6;
  const int lane = tid & 63;
  const int g = lane >> 4;
  const int r16 = lane & 15;

  __shared__ __align__(16) unsigned short A[TM * HH];  // 32 KiB, XOR-swizzled
  __shared__ float la_s[TM + 2];
  __shared__ float scorered[8][TM];
  __shared__ float srow[TM];
  __shared__ float ctxsum[576];     // padded: o -> o + (o>>3)

  char* Ab = (char*)A;
  const unsigned short* bw = wvf + (size_t)w * 32768;  // this wave's B run

  // ---- stage tile 0 ----
  {
    const float* vs = value + ((size_t)b * LL + gx * 64) * HH;
    #pragma unroll
    for (int i = 0; i < 4; ++i) {
      const int c = tid + i * 512;
      const int row = c >> 6, cb = c & 63;
      const float4* s4 = (const float4*)(vs + (size_t)row * HH + cb * 8);
      float4 lo = s4[0], hi = s4[1];
      u16x8 v;
      v[0] = f2bf(lo.x); v[1] = f2bf(lo.y); v[2] = f2bf(lo.z); v[3] = f2bf(lo.w);
      v[4] = f2bf(hi.x); v[5] = f2bf(hi.y); v[6] = f2bf(hi.z); v[7] = f2bf(hi.w);
      *(u16x8*)(Ab + row * 1024 + ((cb * 16) ^ ((row & 7) << 4))) = v;
    }
  }
  ctxsum[tid] = 0.f;
  if (tid < 64) ctxsum[512 + tid] = 0.f;
  if (tid < TM + 2) {
    int l = gx * 64 - 1 + tid;
    la_s[tid] = (l >= 0 && l < LL) ? last_attn[b * LL + l] : 0.f;
  }
  __syncthreads();

  float cacc[8];
  #pragma unroll
  for (int k = 0; k < 8; ++k) cacc[k] = 0.f;

  float4 st[8];
  float lan = 0.f;

  #pragma unroll
  for (int t = 0; t < NT; ++t) {
    const int l0 = gx * 64 + t * TM;

    // ---- K-loop ----
    f32x4 acc[2][4] = {};
    __builtin_amdgcn_s_setprio(1);
    #pragma unroll 2
    for (int kk = 0; kk < 16; ++kk) {
      const unsigned short* bk = bw + (size_t)kk * 4 * 512;
      short8 bf0 = *(const short8*)(bk + (size_t)lane * 8);
      short8 bf1 = *(const short8*)(bk + 512 + (size_t)lane * 8);
      short8 bf2 = *(const short8*)(bk + 1024 + (size_t)lane * 8);
      short8 bf3 = *(const short8*)(bk + 1536 + (size_t)lane * 8);
      const int co = kk * 64 + g * 16;
      const int row0 = r16, row1 = 16 + r16;
      short8 a0 = *(const short8*)(Ab + row0 * 1024 + (co ^ ((row0 & 7) << 4)));
      short8 a1 = *(const short8*)(Ab + row1 * 1024 + (co ^ ((row1 & 7) << 4)));
      acc[0][0] = __builtin_amdgcn_mfma_f32_16x16x32_bf16(a0, bf0, acc[0][0], 0, 0, 0);
      acc[1][0] = __builtin_amdgcn_mfma_f32_16x16x32_bf16(a1, bf0, acc[1][0], 0, 0, 0);
      acc[0][1] = __builtin_amdgcn_mfma_f32_16x16x32_bf16(a0, bf1, acc[0][1], 0, 0, 0);
      acc[1][1] = __builtin_amdgcn_mfma_f32_16x16x32_bf16(a1, bf1, acc[1][1], 0, 0, 0);
      acc[0][2] = __builtin_amdgcn_mfma_f32_16x16x32_bf16(a0, bf2, acc[0][2], 0, 0, 0);
      acc[1][2] = __builtin_amdgcn_mfma_f32_16x16x32_bf16(a1, bf2, acc[1][2], 0, 0, 0);
      acc[0][3] = __builtin_amdgcn_mfma_f32_16x16x32_bf16(a0, bf3, acc[0][3], 0, 0, 0);
      acc[1][3] = __builtin_amdgcn_mfma_f32_16x16x32_bf16(a1, bf3, acc[1][3], 0, 0, 0);
    }
    __builtin_amdgcn_s_setprio(0);

    // ---- score epilogue: e = tanh(acc + base + conv), reduce e*Ws ----
    {
      float basev[4], wsv[4], cw0v[4], cw1v[4], cw2v[4];
      #pragma unroll
      for (int n = 0; n < 4; ++n) {
        const int col = w * 64 + n * 16 + r16;
        basev[n] = base[b * HH + col];
        wsv[n]  = Ws[col];
        cw0v[n] = conv_w[col * 3 + 0];
        cw1v[n] = conv_w[col * 3 + 1];
        cw2v[n] = conv_w[col * 3 + 2];
      }
      #pragma unroll
      for (int m = 0; m < 2; ++m) {
        #pragma unroll
        for (int j = 0; j < 4; ++j) {
          const int row = m * 16 + g * 4 + j;
          const float lam = la_s[row], laz = la_s[row + 1], lap = la_s[row + 2];
          float sum = 0.f;
          #pragma unroll
          for (int n = 0; n < 4; ++n) {
            float e = acc[m][n][j] + basev[n] + cw0v[n] * lam + cw1v[n] * laz + cw2v[n] * lap;
            sum += fast_tanh(e) * wsv[n];
          }
          sum += __shfl_xor(sum, 1, 64);
          sum += __shfl_xor(sum, 2, 64);
          sum += __shfl_xor(sum, 4, 64);
          sum += __shfl_xor(sum, 8, 64);
          if (r16 == 0) scorered[w][row] = sum;
        }
      }
    }
    __syncthreads();

    // ---- T14 issue-early: tile t+1 global loads (acc/consts dead here) ----
    if (t + 1 < NT) {
      const float* vs = value + ((size_t)b * LL + l0 + TM) * HH;
      #pragma unroll
      for (int i = 0; i < 4; ++i) {
        const int c = tid + i * 512;
        const float* p = vs + (size_t)(c >> 6) * HH + (c & 63) * 8;
        st[2 * i]     = *(const float4*)p;
        st[2 * i + 1] = *(const float4*)(p + 4);
      }
      if (tid < TM + 2) {
        int l = l0 + TM - 1 + tid;
        lan = (l < LL) ? last_attn[b * LL + l] : 0.f;
      }
    }

    if (tid < TM) {
      float sc = bs[0];
      #pragma unroll
      for (int ww = 0; ww < 8; ++ww) sc += scorered[ww][tid];
      float s = 1.f / (1.f + __expf(-sc));
      srow[tid] = s;
      attn[b * LL + l0 + tid] = s;   // unnormalized; finalize divides by S
    }
    __syncthreads();

    // ---- ctx partials: wave w rows [w*4, w*4+4), accumulate in regs ----
    #pragma unroll
    for (int i = 0; i < 4; ++i) {
      const int row = w * 4 + i;
      const float s = srow[row];
      const int off = row * 1024 + ((lane * 16) ^ ((row & 7) << 4));
      u16x8 v = *(const u16x8*)(Ab + off);
      #pragma unroll
      for (int k = 0; k < 8; ++k) cacc[k] += s * bf2f(v[k]);
    }

    // ---- write-late: stage tile t+1 into the (now free) buffer ----
    if (t + 1 < NT) {
      __syncthreads();   // everyone done reading buf (ctx reads above)
      #pragma unroll
      for (int i = 0; i < 4; ++i) {
        const int c = tid + i * 512;
        const int row = c >> 6, cb = c & 63;
        u16x8 v;
        v[0] = f2bf(st[2*i].x);   v[1] = f2bf(st[2*i].y);
        v[2] = f2bf(st[2*i].z);   v[3] = f2bf(st[2*i].w);
        v[4] = f2bf(st[2*i+1].x); v[5] = f2bf(st[2*i+1].y);
        v[6] = f2bf(st[2*i+1].z); v[7] = f2bf(st[2*i+1].w);
        *(u16x8*)(Ab + row * 1024 + ((cb * 16) ^ ((row & 7) << 4))) = v;
      }
      if (tid < TM + 2) la_s[tid] = lan;
      __syncthreads();
    }
  }

  // ---- block-level ctx reduce (padded banks), then one global atomic ----
  #pragma unroll
  for (int k = 0; k < 8; ++k) atomicAdd(&ctxsum[lane * 9 + k], cacc[k]);
  __syncthreads();
  atomicAdd(&ctxp[((size_t)(gx & 7) * BB + b) * HH + tid], ctxsum[tid + (tid >> 3)]);
}

// ---------------------------------------------------------------------------
// finalize: per batch: S = sum_l s; attn /= S; out = [sum8(ctxp)/S, query]
// grid B, block 512
// ---------------------------------------------------------------------------
__global__ __launch_bounds__(512) void finalize_kernel(
    const float* __restrict__ query, const float* __restrict__ ctxp,
    float* __restrict__ out, float* __restrict__ attn) {
  const int b = blockIdx.x;
  const int tid = threadIdx.x;
  __shared__ float red[8];
  float s = 0.f;
  for (int l = tid; l < LL; l += 512) s += attn[b * LL + l];
  #pragma unroll
  for (int off = 32; off > 0; off >>= 1) s += __shfl_xor(s, off, 64);
  if ((tid & 63) == 0) red[tid >> 6] = s;
  __syncthreads();
  float S = 0.f;
  #pragma unroll
  for (int i = 0; i < 8; ++i) S += red[i];
  const float inv = 1.f / S;
  float c = 0.f;
  #pragma unroll
  for (int k = 0; k < 8; ++k) c += ctxp[((size_t)k * BB + b) * HH + tid];
  out[b * 2 * HH + tid] = c * inv;
  out[b * 2 * HH + HH + tid] = query[b * HH + tid];
  for (int l = tid; l < LL; l += 512) attn[b * LL + l] *= inv;
}

// ---------------------------------------------------------------------------
extern "C" void kernel_launch(void* const* d_in, const int* in_sizes, int n_in,
                              void* d_out, int out_size, void* d_ws, size_t ws_size,
                              hipStream_t stream) {
  const float* query     = (const float*)d_in[0];
  const float* value     = (const float*)d_in[1];
  const float* last_attn = (const float*)d_in[2];
  const float* conv_w    = (const float*)d_in[3];
  const float* conv_b    = (const float*)d_in[4];
  const float* Wq        = (const float*)d_in[5];
  const float* Wv        = (const float*)d_in[6];
  const float* Ws        = (const float*)d_in[7];
  const float* bs        = (const float*)d_in[8];
  const float* bias      = (const float*)d_in[9];

  float* out  = (float*)d_out;                 // (B, 2H)
  float* attn = out + BB * 2 * HH;             // (B, L)
  float* base = (float*)d_ws;                              // B*H f32
  unsigned short* wvf = (unsigned short*)(base + BB * HH); // 512*512 bf16
  float* ctxp = (float*)(wvf + HH * HH);                   // 8*B*H f32 partials

  hipMemsetAsync(ctxp, 0, 8 * BB * HH * sizeof(float), stream);
  prep_kernel<<<192, 256, 0, stream>>>(query, Wq, bias, conv_b, Wv, base, wvf);
  dim3 grid(LL / (TM * NT), BB);
  main_kernel<<<grid, 512, 0, stream>>>(value, last_attn, conv_w, wvf, Ws, bs,
                                        base, ctxp, attn);
  finalize_kernel<<<BB, 512, 0, stream>>>(query, ctxp, out, attn);
}

// Round 11
// 211.908 us; speedup vs baseline: 2.8841x; 1.1498x over previous
//
#include <hip/hip_runtime.h>
#include <hip/hip_bf16.h>
#include <math.h>

#define BB 32
#define LL 4096
#define HH 512
#define TM 64     // rows per block tile
#define KT 32     // K per slice
#define NS 16     // slices

typedef __attribute__((ext_vector_type(8))) short short8;
typedef __attribute__((ext_vector_type(8))) unsigned short u16x8;
typedef __attribute__((ext_vector_type(4))) unsigned short u16x4;
typedef __attribute__((ext_vector_type(4))) float f32x4;

// manual RNE f32->bf16 (inputs finite randn; no NaN path needed)
__device__ __forceinline__ unsigned short f2bf(float f) {
  unsigned int x;
  __builtin_memcpy(&x, &f, 4);
  x += 0x7fffu + ((x >> 16) & 1u);
  return (unsigned short)(x >> 16);
}
__device__ __forceinline__ float fast_tanh(float x) {
  float e = __expf(2.f * x);
  return 1.f - 2.f / (e + 1.f);
}

// async global->LDS, 16B per lane; dst must be wave-uniform base
__device__ __forceinline__ void glds16(const void* g, void* l) {
  __builtin_amdgcn_global_load_lds(
      (const __attribute__((address_space(1))) void*)g,
      (__attribute__((address_space(3))) void*)l, 16, 0, 0);
}

// ---------------------------------------------------------------------------
// prep: fused {base | wvf2 fragment pack}. grid 192, block 256.
// wvf2 layout: elem idx = f*512 + lane*8 + j, f = (ks*8 + w)*4 + n, holding
// Wv[w*64 + n*16 + (lane&15)][ks*32 + (lane>>4)*8 + j]  -> per (ks,w) a
// contiguous 4KB run = exactly one wave's B for one K-slice (glds source).
// ---------------------------------------------------------------------------
__global__ __launch_bounds__(256) void prep_kernel(
    const float* __restrict__ query, const float* __restrict__ Wq,
    const float* __restrict__ bias, const float* __restrict__ conv_b,
    const float* __restrict__ Wv, float* __restrict__ base,
    unsigned short* __restrict__ wvf2) {
  const int bid = blockIdx.x;
  if (bid < 64) {
    const int b = bid >> 1;
    const int o = ((bid & 1) << 8) + threadIdx.x;
    __shared__ float qrow[HH];
    for (int i = threadIdx.x; i < HH; i += 256) qrow[i] = query[b * HH + i];
    __syncthreads();
    const float* wq = Wq + (size_t)o * HH;
    float acc = 0.f;
    for (int h = 0; h < HH; h += 4) {
      float4 w = *(const float4*)(wq + h);
      acc += w.x * qrow[h] + w.y * qrow[h + 1] + w.z * qrow[h + 2] + w.w * qrow[h + 3];
    }
    base[b * HH + o] = acc + bias[o] + conv_b[o];
  } else {
    const int chunk = (bid - 64) * 256 + threadIdx.x;   // 0..32767
    const int lane = chunk & 63;
    const int f = chunk >> 6;        // (ks*8 + w)*4 + n
    const int n = f & 3;
    const int w = (f >> 2) & 7;
    const int ks = f >> 5;
    const int row = w * 64 + n * 16 + (lane & 15);
    const int col = ks * KT + (lane >> 4) * 8;
    const float* src = Wv + (size_t)row * HH + col;
    u16x8 v;
    #pragma unroll
    for (int j = 0; j < 8; ++j) v[j] = f2bf(src[j]);
    *(u16x8*)(wvf2 + (size_t)chunk * 8) = v;
  }
}

// ---------------------------------------------------------------------------
// main: block = (b, 64-row tile), 512 thr = 8 waves; wave w owns cols
// [w*64, w*64+64) (4 n-frags) over all 64 rows (4 m-frags); acc[4][4].
// K sliced: per slice, B (32KB) arrives via global_load_lds (no VGPR ->
// no spill), A-slice (64x32 f32) reg-routed w/ cvt into padded LDS.
// Double-buffered; ONE barrier per slice; prefetch issued before compute.
// ctx pass re-reads value rows from global (L2/L3-hot).
// grid (64, 32), block 512
// ---------------------------------------------------------------------------
__global__ __launch_bounds__(512, 4) void main_kernel(
    const float* __restrict__ value, const float* __restrict__ last_attn,
    const float* __restrict__ conv_w, const unsigned short* __restrict__ wvf2,
    const float* __restrict__ Ws, const float* __restrict__ bs,
    const float* __restrict__ base, float* __restrict__ ctxp,
    float* __restrict__ attn) {
  const int b = blockIdx.y;
  const int gx = blockIdx.x;
  const int l0 = gx * TM;
  const int tid = threadIdx.x;
  const int w = tid >> 6;
  const int lane = tid & 63;
  const int g = lane >> 4;
  const int r16 = lane & 15;

  __shared__ __align__(16) unsigned short Bs[2][8 * 4 * 512];  // 2 x 32 KiB
  __shared__ __align__(16) unsigned short As[2][TM * 40];      // 2 x 5 KiB, pad 80B rows
  __shared__ float la_s[TM + 2];
  __shared__ float sacc[TM];
  __shared__ float srow[TM];
  __shared__ float ctxsum[576];   // padded lane*9+k

  // per-thread A-stage coords: row = tid>>3, k-quad = (tid&7)*4
  const int ar = tid >> 3;
  const int ac = (tid & 7) * 4;
  const float* asrc = value + ((size_t)b * LL + l0 + ar) * HH + ac;

  // ---- prologue: stage slice 0 ----
  #pragma unroll
  for (int i = 0; i < 4; ++i)
    glds16(wvf2 + (((size_t)(0 * 8 + w) * 4 + i) * 512) + lane * 8,
           &Bs[0][w * 2048 + i * 512]);
  {
    float4 av = *(const float4*)(asrc + 0 * KT);
    u16x4 v;
    v[0] = f2bf(av.x); v[1] = f2bf(av.y); v[2] = f2bf(av.z); v[3] = f2bf(av.w);
    *(u16x4*)(&As[0][ar * 40 + ac]) = v;
  }
  ctxsum[tid] = 0.f;
  if (tid < 64) ctxsum[512 + tid] = 0.f;
  if (tid < TM) sacc[tid] = bs[0];
  if (tid < TM + 2) {
    int l = l0 - 1 + tid;
    la_s[tid] = (l >= 0 && l < LL) ? last_attn[b * LL + l] : 0.f;
  }
  __syncthreads();   // drains vmcnt(0): B slice 0 landed

  // ---- K loop over 16 slices, double-buffered ----
  f32x4 acc[4][4] = {};
  for (int ks = 0; ks < NS; ++ks) {
    const int cur = ks & 1;
    const int nxt = cur ^ 1;

    if (ks < NS - 1) {
      // issue next slice's B directly to LDS (zero VGPR held)
      #pragma unroll
      for (int i = 0; i < 4; ++i)
        glds16(wvf2 + (((size_t)((ks + 1) * 8 + w) * 4 + i) * 512) + lane * 8,
               &Bs[nxt][w * 2048 + i * 512]);
      // issue next A-slice load; consumed by ds_write below (compiler waits)
      float4 av = *(const float4*)(asrc + (ks + 1) * KT);

      // compute current slice from LDS
      short8 a0 = *(const short8*)(&As[cur][(0 * 16 + r16) * 40 + g * 8]);
      short8 a1 = *(const short8*)(&As[cur][(1 * 16 + r16) * 40 + g * 8]);
      short8 a2 = *(const short8*)(&As[cur][(2 * 16 + r16) * 40 + g * 8]);
      short8 a3 = *(const short8*)(&As[cur][(3 * 16 + r16) * 40 + g * 8]);
      short8 b0 = *(const short8*)(&Bs[cur][w * 2048 + 0 * 512 + lane * 8]);
      short8 b1 = *(const short8*)(&Bs[cur][w * 2048 + 1 * 512 + lane * 8]);
      short8 b2 = *(const short8*)(&Bs[cur][w * 2048 + 2 * 512 + lane * 8]);
      short8 b3 = *(const short8*)(&Bs[cur][w * 2048 + 3 * 512 + lane * 8]);
      acc[0][0] = __builtin_amdgcn_mfma_f32_16x16x32_bf16(a0, b0, acc[0][0], 0, 0, 0);
      acc[1][0] = __builtin_amdgcn_mfma_f32_16x16x32_bf16(a1, b0, acc[1][0], 0, 0, 0);
      acc[2][0] = __builtin_amdgcn_mfma_f32_16x16x32_bf16(a2, b0, acc[2][0], 0, 0, 0);
      acc[3][0] = __builtin_amdgcn_mfma_f32_16x16x32_bf16(a3, b0, acc[3][0], 0, 0, 0);
      acc[0][1] = __builtin_amdgcn_mfma_f32_16x16x32_bf16(a0, b1, acc[0][1], 0, 0, 0);
      acc[1][1] = __builtin_amdgcn_mfma_f32_16x16x32_bf16(a1, b1, acc[1][1], 0, 0, 0);
      acc[2][1] = __builtin_amdgcn_mfma_f32_16x16x32_bf16(a2, b1, acc[2][1], 0, 0, 0);
      acc[3][1] = __builtin_amdgcn_mfma_f32_16x16x32_bf16(a3, b1, acc[3][1], 0, 0, 0);
      acc[0][2] = __builtin_amdgcn_mfma_f32_16x16x32_bf16(a0, b2, acc[0][2], 0, 0, 0);
      acc[1][2] = __builtin_amdgcn_mfma_f32_16x16x32_bf16(a1, b2, acc[1][2], 0, 0, 0);
      acc[2][2] = __builtin_amdgcn_mfma_f32_16x16x32_bf16(a2, b2, acc[2][2], 0, 0, 0);
      acc[3][2] = __builtin_amdgcn_mfma_f32_16x16x32_bf16(a3, b2, acc[3][2], 0, 0, 0);
      acc[0][3] = __builtin_amdgcn_mfma_f32_16x16x32_bf16(a0, b3, acc[0][3], 0, 0, 0);
      acc[1][3] = __builtin_amdgcn_mfma_f32_16x16x32_bf16(a1, b3, acc[1][3], 0, 0, 0);
      acc[2][3] = __builtin_amdgcn_mfma_f32_16x16x32_bf16(a2, b3, acc[2][3], 0, 0, 0);
      acc[3][3] = __builtin_amdgcn_mfma_f32_16x16x32_bf16(a3, b3, acc[3][3], 0, 0, 0);

      // write next A-slice (waits only the float4 above)
      u16x4 v;
      v[0] = f2bf(av.x); v[1] = f2bf(av.y); v[2] = f2bf(av.z); v[3] = f2bf(av.w);
      *(u16x4*)(&As[nxt][ar * 40 + ac]) = v;
    } else {
      short8 a0 = *(const short8*)(&As[cur][(0 * 16 + r16) * 40 + g * 8]);
      short8 a1 = *(const short8*)(&As[cur][(1 * 16 + r16) * 40 + g * 8]);
      short8 a2 = *(const short8*)(&As[cur][(2 * 16 + r16) * 40 + g * 8]);
      short8 a3 = *(const short8*)(&As[cur][(3 * 16 + r16) * 40 + g * 8]);
      short8 b0 = *(const short8*)(&Bs[cur][w * 2048 + 0 * 512 + lane * 8]);
      short8 b1 = *(const short8*)(&Bs[cur][w * 2048 + 1 * 512 + lane * 8]);
      short8 b2 = *(const short8*)(&Bs[cur][w * 2048 + 2 * 512 + lane * 8]);
      short8 b3 = *(const short8*)(&Bs[cur][w * 2048 + 3 * 512 + lane * 8]);
      acc[0][0] = __builtin_amdgcn_mfma_f32_16x16x32_bf16(a0, b0, acc[0][0], 0, 0, 0);
      acc[1][0] = __builtin_amdgcn_mfma_f32_16x16x32_bf16(a1, b0, acc[1][0], 0, 0, 0);
      acc[2][0] = __builtin_amdgcn_mfma_f32_16x16x32_bf16(a2, b0, acc[2][0], 0, 0, 0);
      acc[3][0] = __builtin_amdgcn_mfma_f32_16x16x32_bf16(a3, b0, acc[3][0], 0, 0, 0);
      acc[0][1] = __builtin_amdgcn_mfma_f32_16x16x32_bf16(a0, b1, acc[0][1], 0, 0, 0);
      acc[1][1] = __builtin_amdgcn_mfma_f32_16x16x32_bf16(a1, b1, acc[1][1], 0, 0, 0);
      acc[2][1] = __builtin_amdgcn_mfma_f32_16x16x32_bf16(a2, b1, acc[2][1], 0, 0, 0);
      acc[3][1] = __builtin_amdgcn_mfma_f32_16x16x32_bf16(a3, b1, acc[3][1], 0, 0, 0);
      acc[0][2] = __builtin_amdgcn_mfma_f32_16x16x32_bf16(a0, b2, acc[0][2], 0, 0, 0);
      acc[1][2] = __builtin_amdgcn_mfma_f32_16x16x32_bf16(a1, b2, acc[1][2], 0, 0, 0);
      acc[2][2] = __builtin_amdgcn_mfma_f32_16x16x32_bf16(a2, b2, acc[2][2], 0, 0, 0);
      acc[3][2] = __builtin_amdgcn_mfma_f32_16x16x32_bf16(a3, b2, acc[3][2], 0, 0, 0);
      acc[0][3] = __builtin_amdgcn_mfma_f32_16x16x32_bf16(a0, b3, acc[0][3], 0, 0, 0);
      acc[1][3] = __builtin_amdgcn_mfma_f32_16x16x32_bf16(a1, b3, acc[1][3], 0, 0, 0);
      acc[2][3] = __builtin_amdgcn_mfma_f32_16x16x32_bf16(a2, b3, acc[2][3], 0, 0, 0);
      acc[3][3] = __builtin_amdgcn_mfma_f32_16x16x32_bf16(a3, b3, acc[3][3], 0, 0, 0);
    }
    __syncthreads();   // vmcnt(0): next B landed; As[nxt] visible
  }

  // ---- score epilogue: e = tanh(acc + base + conv), reduce e*Ws ----
  {
    float basev[4], wsv[4], cw0v[4], cw1v[4], cw2v[4];
    #pragma unroll
    for (int n = 0; n < 4; ++n) {
      const int col = w * 64 + n * 16 + r16;
      basev[n] = base[b * HH + col];
      wsv[n]  = Ws[col];
      cw0v[n] = conv_w[col * 3 + 0];
      cw1v[n] = conv_w[col * 3 + 1];
      cw2v[n] = conv_w[col * 3 + 2];
    }
    #pragma unroll
    for (int m = 0; m < 4; ++m) {
      #pragma unroll
      for (int j = 0; j < 4; ++j) {
        const int row = m * 16 + g * 4 + j;
        const float lam = la_s[row], laz = la_s[row + 1], lap = la_s[row + 2];
        float sum = 0.f;
        #pragma unroll
        for (int n = 0; n < 4; ++n) {
          float e = acc[m][n][j] + basev[n] + cw0v[n] * lam + cw1v[n] * laz + cw2v[n] * lap;
          sum += fast_tanh(e) * wsv[n];
        }
        sum += __shfl_xor(sum, 1, 64);
        sum += __shfl_xor(sum, 2, 64);
        sum += __shfl_xor(sum, 4, 64);
        sum += __shfl_xor(sum, 8, 64);
        if (r16 == 0) atomicAdd(&sacc[row], sum);
      }
    }
  }
  __syncthreads();
  if (tid < TM) {
    float s = 1.f / (1.f + __expf(-sacc[tid]));
    srow[tid] = s;
    attn[b * LL + l0 + tid] = s;   // unnormalized; finalize divides by S
  }
  __syncthreads();

  // ---- ctx partials: wave w rows [w*8, w*8+8) re-read from global ----
  {
    float cacc[8];
    #pragma unroll
    for (int k = 0; k < 8; ++k) cacc[k] = 0.f;
    const float* vr = value + ((size_t)b * LL + l0 + w * 8) * HH + lane * 8;
    #pragma unroll
    for (int i = 0; i < 8; ++i) {
      float4 x0 = *(const float4*)(vr + (size_t)i * HH);
      float4 x1 = *(const float4*)(vr + (size_t)i * HH + 4);
      const float s = srow[w * 8 + i];
      cacc[0] += s * x0.x; cacc[1] += s * x0.y; cacc[2] += s * x0.z; cacc[3] += s * x0.w;
      cacc[4] += s * x1.x; cacc[5] += s * x1.y; cacc[6] += s * x1.z; cacc[7] += s * x1.w;
    }
    #pragma unroll
    for (int k = 0; k < 8; ++k) atomicAdd(&ctxsum[lane * 9 + k], cacc[k]);
  }
  __syncthreads();
  atomicAdd(&ctxp[((size_t)(gx & 7) * BB + b) * HH + tid], ctxsum[tid + (tid >> 3)]);
}

// ---------------------------------------------------------------------------
// finalize: per batch: S = sum_l s; attn /= S; out = [sum8(ctxp)/S, query]
// grid B, block 512
// ---------------------------------------------------------------------------
__global__ __launch_bounds__(512) void finalize_kernel(
    const float* __restrict__ query, const float* __restrict__ ctxp,
    float* __restrict__ out, float* __restrict__ attn) {
  const int b = blockIdx.x;
  const int tid = threadIdx.x;
  __shared__ float red[8];
  float s = 0.f;
  for (int l = tid; l < LL; l += 512) s += attn[b * LL + l];
  #pragma unroll
  for (int off = 32; off > 0; off >>= 1) s += __shfl_xor(s, off, 64);
  if ((tid & 63) == 0) red[tid >> 6] = s;
  __syncthreads();
  float S = 0.f;
  #pragma unroll
  for (int i = 0; i < 8; ++i) S += red[i];
  const float inv = 1.f / S;
  float c = 0.f;
  #pragma unroll
  for (int k = 0; k < 8; ++k) c += ctxp[((size_t)k * BB + b) * HH + tid];
  out[b * 2 * HH + tid] = c * inv;
  out[b * 2 * HH + HH + tid] = query[b * HH + tid];
  for (int l = tid; l < LL; l += 512) attn[b * LL + l] *= inv;
}

// ---------------------------------------------------------------------------
extern "C" void kernel_launch(void* const* d_in, const int* in_sizes, int n_in,
                              void* d_out, int out_size, void* d_ws, size_t ws_size,
                              hipStream_t stream) {
  const float* query     = (const float*)d_in[0];
  const float* value     = (const float*)d_in[1];
  const float* last_attn = (const float*)d_in[2];
  const float* conv_w    = (const float*)d_in[3];
  const float* conv_b    = (const float*)d_in[4];
  const float* Wq        = (const float*)d_in[5];
  const float* Wv        = (const float*)d_in[6];
  const float* Ws        = (const float*)d_in[7];
  const float* bs        = (const float*)d_in[8];
  const float* bias      = (const float*)d_in[9];

  float* out  = (float*)d_out;                 // (B, 2H)
  float* attn = out + BB * 2 * HH;             // (B, L)
  float* base = (float*)d_ws;                               // B*H f32
  unsigned short* wvf2 = (unsigned short*)(base + BB * HH); // 512*512 bf16
  float* ctxp = (float*)(wvf2 + HH * HH);                   // 8*B*H f32 partials

  hipMemsetAsync(ctxp, 0, 8 * BB * HH * sizeof(float), stream);
  prep_kernel<<<192, 256, 0, stream>>>(query, Wq, bias, conv_b, Wv, base, wvf2);
  dim3 grid(LL / TM, BB);
  main_kernel<<<grid, 512, 0, stream>>>(value, last_attn, conv_w, wvf2, Ws, bs,
                                        base, ctxp, attn);
  finalize_kernel<<<BB, 512, 0, stream>>>(query, ctxp, out, attn);
}

// Round 12
// 199.258 us; speedup vs baseline: 3.0672x; 1.0635x over previous
//
#include <hip/hip_runtime.h>
#include <hip/hip_bf16.h>
#include <math.h>

#define BB 32
#define LL 4096
#define HH 512
#define TM 128   // rows per block tile

typedef __attribute__((ext_vector_type(8))) short short8;
typedef __attribute__((ext_vector_type(8))) unsigned short u16x8;
typedef __attribute__((ext_vector_type(4))) float f32x4;

// manual RNE f32->bf16 (inputs finite randn; no NaN path needed)
__device__ __forceinline__ unsigned short f2bf(float f) {
  unsigned int x;
  __builtin_memcpy(&x, &f, 4);
  x += 0x7fffu + ((x >> 16) & 1u);
  return (unsigned short)(x >> 16);
}
__device__ __forceinline__ float bf2f(unsigned short u) {
  unsigned int x = ((unsigned int)u) << 16;
  float f;
  __builtin_memcpy(&f, &x, 4);
  return f;
}
__device__ __forceinline__ float fast_tanh(float x) {
  float e = __expf(2.f * x);
  return 1.f - 2.f / (e + 1.f);
}

// ---------------------------------------------------------------------------
// prep: fused {base | wvf fragment pack}. grid 192, block 256.
// wvf layout (R4's): chunk = nb*1024 + kk*64 + lane, frag holds
// Wv[nb*16 + (lane&15)][kk*32 + (lane>>4)*8 + j], j=0..7.
// ---------------------------------------------------------------------------
__global__ __launch_bounds__(256) void prep_kernel(
    const float* __restrict__ query, const float* __restrict__ Wq,
    const float* __restrict__ bias, const float* __restrict__ conv_b,
    const float* __restrict__ Wv, float* __restrict__ base,
    unsigned short* __restrict__ wvf) {
  const int bid = blockIdx.x;
  if (bid < 64) {
    const int b = bid >> 1;
    const int o = ((bid & 1) << 8) + threadIdx.x;
    __shared__ float qrow[HH];
    for (int i = threadIdx.x; i < HH; i += 256) qrow[i] = query[b * HH + i];
    __syncthreads();
    const float* wq = Wq + (size_t)o * HH;
    float acc = 0.f;
    for (int h = 0; h < HH; h += 4) {
      float4 w = *(const float4*)(wq + h);
      acc += w.x * qrow[h] + w.y * qrow[h + 1] + w.z * qrow[h + 2] + w.w * qrow[h + 3];
    }
    base[b * HH + o] = acc + bias[o] + conv_b[o];
  } else {
    const int chunk = (bid - 64) * 256 + threadIdx.x;
    const int l = chunk & 63;
    const int kk = (chunk >> 6) & 15;
    const int nb = chunk >> 10;
    const int row = nb * 16 + (l & 15);
    const int colf = kk * 32 + (l >> 4) * 8;
    const float* src = Wv + (size_t)row * HH + colf;
    u16x8 v;
    #pragma unroll
    for (int j = 0; j < 8; ++j) v[j] = f2bf(src[j]);
    *(u16x8*)(wvf + (size_t)chunk * 8) = v;
  }
}

// ---------------------------------------------------------------------------
// main: block = (b, 128-row tile), 1024 thr = 16 waves = 2 row-halves (rh)
// x 8 col-groups (cg). Wave (rh,cg) computes rows [rh*64,rh*64+64) x cols
// [cg*64, cg*64+64): acc[4][4]. Per-CU B-traffic through L1 = 4 MB (half of
// all previous rounds; the rh-pair re-hits each B line in L1).
// A tile 128x512 bf16 in LDS (XOR-swizzled, 128 KiB). 1 block/CU.
// grid (32, 32), block 1024
// ---------------------------------------------------------------------------
__global__ __launch_bounds__(1024, 4) void main_kernel(
    const float* __restrict__ value, const float* __restrict__ last_attn,
    const float* __restrict__ conv_w, const unsigned short* __restrict__ wvf,
    const float* __restrict__ Ws, const float* __restrict__ bs,
    const float* __restrict__ base, float* __restrict__ ctxp,
    float* __restrict__ attn) {
  const int b = blockIdx.y;
  const int gx = blockIdx.x;
  const int l0 = gx * TM;
  const int tid = threadIdx.x;
  const int w = tid >> 6;          // 0..15
  const int rh = w >> 3;           // row half
  const int cg = w & 7;            // col group
  const int lane = tid & 63;
  const int g = lane >> 4;
  const int r16 = lane & 15;

  __shared__ __align__(16) unsigned short A[TM * HH];  // 128 KiB, swizzled
  __shared__ float la_s[TM + 2];
  __shared__ float scorered[8][TM];   // [cg][row]
  __shared__ float srow[TM];
  __shared__ float ctxsum[576];       // padded col + (col>>3)

  char* Ab = (char*)A;

  // ---- stage value tile: f32 -> bf16, swizzled LDS (8 chunks/thread) ----
  const float* vsrc = value + (size_t)(b * LL + l0) * HH;
  #pragma unroll
  for (int i = 0; i < 8; ++i) {
    const int c = tid + i * 1024;       // 8192 chunks of 8 bf16
    const int row = c >> 6;
    const int cb = c & 63;
    const float4* s4 = (const float4*)(vsrc + (size_t)row * HH + cb * 8);
    float4 lo = s4[0], hi = s4[1];
    u16x8 v;
    v[0] = f2bf(lo.x); v[1] = f2bf(lo.y); v[2] = f2bf(lo.z); v[3] = f2bf(lo.w);
    v[4] = f2bf(hi.x); v[5] = f2bf(hi.y); v[6] = f2bf(hi.z); v[7] = f2bf(hi.w);
    const int off = row * 1024 + ((cb * 16) ^ ((row & 7) << 4));
    *(u16x8*)(Ab + off) = v;
  }
  if (tid < 576 - TM - 2) {}  // (no-op; keep structure simple)
  if (tid < 576) ctxsum[tid] = 0.f;
  if (tid < TM + 2) {
    int l = l0 - 1 + tid;
    la_s[tid] = (l >= 0 && l < LL) ? last_attn[b * LL + l] : 0.f;
  }
  __syncthreads();

  // ---- K-loop: acc[m 0..4][n 0..4] over 16 kk steps ----
  f32x4 acc[4][4] = {};
  #pragma unroll 2
  for (int kk = 0; kk < 16; ++kk) {
    const int co = kk * 64 + g * 16;
    short8 a0, a1, a2, a3;
    {
      const int row0 = rh * 64 + r16;
      const int row1 = rh * 64 + 16 + r16;
      const int row2 = rh * 64 + 32 + r16;
      const int row3 = rh * 64 + 48 + r16;
      a0 = *(const short8*)(Ab + row0 * 1024 + (co ^ ((row0 & 7) << 4)));
      a1 = *(const short8*)(Ab + row1 * 1024 + (co ^ ((row1 & 7) << 4)));
      a2 = *(const short8*)(Ab + row2 * 1024 + (co ^ ((row2 & 7) << 4)));
      a3 = *(const short8*)(Ab + row3 * 1024 + (co ^ ((row3 & 7) << 4)));
    }
    #pragma unroll
    for (int n = 0; n < 4; ++n) {
      short8 bf = *(const short8*)(wvf + ((size_t)((cg * 4 + n) * 16 + kk) * 64 + lane) * 8);
      acc[0][n] = __builtin_amdgcn_mfma_f32_16x16x32_bf16(a0, bf, acc[0][n], 0, 0, 0);
      acc[1][n] = __builtin_amdgcn_mfma_f32_16x16x32_bf16(a1, bf, acc[1][n], 0, 0, 0);
      acc[2][n] = __builtin_amdgcn_mfma_f32_16x16x32_bf16(a2, bf, acc[2][n], 0, 0, 0);
      acc[3][n] = __builtin_amdgcn_mfma_f32_16x16x32_bf16(a3, bf, acc[3][n], 0, 0, 0);
    }
  }

  // ---- score epilogue: e = tanh(acc + base + conv), reduce e*Ws ----
  {
    float basev[4], wsv[4], cw0v[4], cw1v[4], cw2v[4];
    #pragma unroll
    for (int n = 0; n < 4; ++n) {
      const int col = cg * 64 + n * 16 + r16;
      basev[n] = base[b * HH + col];
      wsv[n]  = Ws[col];
      cw0v[n] = conv_w[col * 3 + 0];
      cw1v[n] = conv_w[col * 3 + 1];
      cw2v[n] = conv_w[col * 3 + 2];
    }
    #pragma unroll
    for (int m = 0; m < 4; ++m) {
      #pragma unroll
      for (int j = 0; j < 4; ++j) {
        const int row = rh * 64 + m * 16 + g * 4 + j;
        const float lam = la_s[row], laz = la_s[row + 1], lap = la_s[row + 2];
        float sum = 0.f;
        #pragma unroll
        for (int n = 0; n < 4; ++n) {
          float e = acc[m][n][j] + basev[n] + cw0v[n] * lam + cw1v[n] * laz + cw2v[n] * lap;
          sum += fast_tanh(e) * wsv[n];
        }
        sum += __shfl_xor(sum, 1, 64);
        sum += __shfl_xor(sum, 2, 64);
        sum += __shfl_xor(sum, 4, 64);
        sum += __shfl_xor(sum, 8, 64);
        if (r16 == 0) scorered[cg][row] = sum;   // unique (cg,row) writer
      }
    }
  }
  __syncthreads();
  if (tid < TM) {
    float sc = bs[0];
    #pragma unroll
    for (int c = 0; c < 8; ++c) sc += scorered[c][tid];
    float s = 1.f / (1.f + __expf(-sc));
    srow[tid] = s;
    attn[b * LL + l0 + tid] = s;   // unnormalized; finalize divides by S
  }
  __syncthreads();

  // ---- ctx partials: wave w rows [w*8, w*8+8), lane owns 8 cols ----
  {
    float cacc[8];
    #pragma unroll
    for (int k = 0; k < 8; ++k) cacc[k] = 0.f;
    #pragma unroll
    for (int i = 0; i < 8; ++i) {
      const int row = w * 8 + i;
      const float s = srow[row];
      const int off = row * 1024 + ((lane * 16) ^ ((row & 7) << 4));
      u16x8 v = *(const u16x8*)(Ab + off);
      #pragma unroll
      for (int k = 0; k < 8; ++k) cacc[k] += s * bf2f(v[k]);
    }
    #pragma unroll
    for (int k = 0; k < 8; ++k) atomicAdd(&ctxsum[lane * 9 + k], cacc[k]);
  }
  __syncthreads();
  if (tid < HH)
    atomicAdd(&ctxp[((size_t)(gx & 7) * BB + b) * HH + tid], ctxsum[tid + (tid >> 3)]);
}

// ---------------------------------------------------------------------------
// finalize: per batch: S = sum_l s; attn /= S; out = [sum8(ctxp)/S, query]
// grid B, block 512
// ---------------------------------------------------------------------------
__global__ __launch_bounds__(512) void finalize_kernel(
    const float* __restrict__ query, const float* __restrict__ ctxp,
    float* __restrict__ out, float* __restrict__ attn) {
  const int b = blockIdx.x;
  const int tid = threadIdx.x;
  __shared__ float red[8];
  float s = 0.f;
  for (int l = tid; l < LL; l += 512) s += attn[b * LL + l];
  #pragma unroll
  for (int off = 32; off > 0; off >>= 1) s += __shfl_xor(s, off, 64);
  if ((tid & 63) == 0) red[tid >> 6] = s;
  __syncthreads();
  float S = 0.f;
  #pragma unroll
  for (int i = 0; i < 8; ++i) S += red[i];
  const float inv = 1.f / S;
  float c = 0.f;
  #pragma unroll
  for (int k = 0; k < 8; ++k) c += ctxp[((size_t)k * BB + b) * HH + tid];
  out[b * 2 * HH + tid] = c * inv;
  out[b * 2 * HH + HH + tid] = query[b * HH + tid];
  for (int l = tid; l < LL; l += 512) attn[b * LL + l] *= inv;
}

// ---------------------------------------------------------------------------
extern "C" void kernel_launch(void* const* d_in, const int* in_sizes, int n_in,
                              void* d_out, int out_size, void* d_ws, size_t ws_size,
                              hipStream_t stream) {
  const float* query     = (const float*)d_in[0];
  const float* value     = (const float*)d_in[1];
  const float* last_attn = (const float*)d_in[2];
  const float* conv_w    = (const float*)d_in[3];
  const float* conv_b    = (const float*)d_in[4];
  const float* Wq        = (const float*)d_in[5];
  const float* Wv        = (const float*)d_in[6];
  const float* Ws        = (const float*)d_in[7];
  const float* bs        = (const float*)d_in[8];
  const float* bias      = (const float*)d_in[9];

  float* out  = (float*)d_out;                 // (B, 2H)
  float* attn = out + BB * 2 * HH;             // (B, L)
  float* base = (float*)d_ws;                               // B*H f32
  unsigned short* wvf = (unsigned short*)(base + BB * HH);  // 512*512 bf16
  float* ctxp = (float*)(wvf + HH * HH);                    // 8*B*H f32 partials

  hipMemsetAsync(ctxp, 0, 8 * BB * HH * sizeof(float), stream);
  prep_kernel<<<192, 256, 0, stream>>>(query, Wq, bias, conv_b, Wv, base, wvf);
  dim3 grid(LL / TM, BB);
  main_kernel<<<grid, 1024, 0, stream>>>(value, last_attn, conv_w, wvf, Ws, bs,
                                         base, ctxp, attn);
  finalize_kernel<<<BB, 512, 0, stream>>>(query, ctxp, out, attn);
}